// Round 6
// baseline (51.590 us; speedup 1.0000x reference)
//
#include <hip/hip_runtime.h>
#include <hip/hip_bf16.h>

#define S_LEN 2048
#define K_NB  64

typedef __attribute__((ext_vector_type(8))) short bf16x8;
typedef __attribute__((ext_vector_type(4))) float f32x4;
typedef __attribute__((ext_vector_type(4))) unsigned int u32x4;

__device__ inline unsigned short f2b(float f) {
    unsigned u = __builtin_bit_cast(unsigned, f);
    return (unsigned short)((u + 0x7FFFu + ((u >> 16) & 1u)) >> 16);  // RNE
}

// XOR-swizzled byte offset in a [rows][64] bf16 LDS tile (T2: kills the
// 16-way ds_read_b128 conflict on the stride-128B column reads).
__device__ inline int swoff(int row, int k) {
    int o = row * 128 + k * 2;
    return o ^ ((row & 7) << 4);
}

// ---------------------------------------------------------------------------
// prep: b<128  : W_in  -> Wb_in  bf16 [k][n] (straight convert, coalesced)
//       b<256  : W_out -> Wt_out bf16 [n][k] (transpose + convert)
//       b<264  : cantor measure (fp32-faithful; exp via double = corr-rounded)
//       b<266  : bc[n] = b_in @ W_out + b_out  (fp32)
// ---------------------------------------------------------------------------
__global__ __launch_bounds__(256) void prep_kernel(
    const float* __restrict__ W_in, const float* __restrict__ W_out,
    const float* __restrict__ b_in, const float* __restrict__ b_out,
    unsigned short* __restrict__ Wb_in, unsigned short* __restrict__ Wt_out,
    float* __restrict__ cmf, float* __restrict__ bc) {
    int b = blockIdx.x, tid = threadIdx.x;
    if (b < 128) {
        int base = (b * 256 + tid) * 8;
        float4 v0 = *(const float4*)(W_in + base);
        float4 v1 = *(const float4*)(W_in + base + 4);
        unsigned short t[8] = { f2b(v0.x), f2b(v0.y), f2b(v0.z), f2b(v0.w),
                                f2b(v1.x), f2b(v1.y), f2b(v1.z), f2b(v1.w) };
        *(u32x4*)(Wb_in + base) = *(u32x4*)t;
    } else if (b < 256) {
        int u = (b - 128) * 256 + tid;
        int n = u & 511, kc = (u >> 9) * 8;
        unsigned short t[8];
        #pragma unroll
        for (int j = 0; j < 8; ++j) t[j] = f2b(W_out[(size_t)(kc + j) * 512 + n]);
        *(u32x4*)(Wt_out + (size_t)n * 512 + kc) = *(u32x4*)t;
    } else if (b < 264) {
        int s = (b - 256) * 256 + tid;
        float pos = ((float)s + 0.5f) * (1.0f / 2048.0f);
        float cm = 0.0f, scale = 1.0f, lvlw = 1.0f;
        #pragma unroll
        for (int k = 1; k <= 5; ++k) {
            scale *= 3.0f; lvlw *= 0.5f;
            float y = fmodf(pos * scale, 3.0f);
            float d0 = y - 0.5f, d1 = y - 1.5f, d2 = y - 2.5f;
            float l0 = -(d0 * d0) * 4.0f;   // /(0.25+1e-10) == *4 in fp32
            float l1 = -(d1 * d1) * 4.0f;
            float l2 = -(d2 * d2) * 4.0f;
            float m = fmaxf(l0, fmaxf(l1, l2));
            float e0 = (float)exp((double)(l0 - m));
            float e1 = (float)exp((double)(l1 - m));
            float e2 = (float)exp((double)(l2 - m));
            float sum = (e0 + e1) + e2;
            float p1 = e1 / sum, p2 = e2 / sum;
            cm += (p2 + 0.5f * p1) * lvlw;
        }
        cmf[s] = cm;
    } else {
        int n = (b - 264) * 256 + tid;
        float acc = b_out[n];
        #pragma unroll 8
        for (int j = 0; j < 512; ++j) acc += b_in[j] * W_out[(size_t)j * 512 + n];
        bc[n] = acc;
    }
}

// ---------------------------------------------------------------------------
// mid: b<32  : Wct[n][k] = sum_j Wt_out[n][j]*Wb_in[k][j]  ( = (W_in@W_out)^T )
//              bf16 MFMA, 64x128 tile, BK=64, reg-pipelined (round-5 structure)
//      b>=32 : exact-equality grouping, 4 s per block (one per wave), ballot
//              prefix preserves ascending-j order = lax.top_k tie-break.
// ---------------------------------------------------------------------------
__global__ __launch_bounds__(256) void mid_kernel(
    const float* __restrict__ cmf, int* __restrict__ routes,
    int* __restrict__ counts,
    const unsigned short* __restrict__ Wt_out,
    const unsigned short* __restrict__ Wb_in,
    unsigned short* __restrict__ Wct) {
    __shared__ char lds[(64 + 128) * 64 * 2];   // A 8KB | B 16KB
    int b = blockIdx.x, tid = threadIdx.x;
    int wid = tid >> 6, lane = tid & 63;
    if (b < 32) {
        char* As = lds;
        char* Bs = lds + 64 * 64 * 2;
        int bm = b >> 2, bn = b & 3;
        int wr = wid >> 1, wc = wid & 1;
        int l15 = lane & 15, l4 = lane >> 4;
        int arow = tid >> 2, akq = (tid & 3) * 16;
        int brow = tid >> 1, bkh = (tid & 1) * 32;
        const unsigned short* asrc = Wt_out + (size_t)(bm * 64 + arow) * 512 + akq;
        const unsigned short* bsrc = Wb_in + (size_t)(bn * 128 + brow) * 512 + bkh;
        u32x4 arg[2], brg[4];
        auto la = [&](int k0) {
            arg[0] = *(const u32x4*)(asrc + k0);
            arg[1] = *(const u32x4*)(asrc + k0 + 8);
        };
        auto lb = [&](int k0) {
            #pragma unroll
            for (int i = 0; i < 4; ++i) brg[i] = *(const u32x4*)(bsrc + k0 + i * 8);
        };
        f32x4 acc[2][4] = {};
        la(0); lb(0);
        for (int k0 = 0; k0 < 512; k0 += 64) {
            *(u32x4*)(As + swoff(arow, akq))     = arg[0];
            *(u32x4*)(As + swoff(arow, akq + 8)) = arg[1];
            #pragma unroll
            for (int i = 0; i < 4; ++i)
                *(u32x4*)(Bs + swoff(brow, bkh + i * 8)) = brg[i];
            __syncthreads();
            if (k0 + 64 < 512) { la(k0 + 64); lb(k0 + 64); }
            #pragma unroll
            for (int kk = 0; kk < 2; ++kk) {
                const int kb = kk * 32 + l4 * 8;
                bf16x8 af[2], bg[4];
                #pragma unroll
                for (int m = 0; m < 2; ++m)
                    af[m] = *(bf16x8*)(As + swoff(wr * 32 + m * 16 + l15, kb));
                #pragma unroll
                for (int n = 0; n < 4; ++n)
                    bg[n] = *(bf16x8*)(Bs + swoff(wc * 64 + n * 16 + l15, kb));
                #pragma unroll
                for (int m = 0; m < 2; ++m)
                    #pragma unroll
                    for (int n = 0; n < 4; ++n)
                        acc[m][n] = __builtin_amdgcn_mfma_f32_16x16x32_bf16(
                            af[m], bg[n], acc[m][n], 0, 0, 0);
            }
            __syncthreads();
        }
        #pragma unroll
        for (int m = 0; m < 2; ++m)
            #pragma unroll
            for (int r = 0; r < 4; ++r) {
                int row = bm * 64 + wr * 32 + m * 16 + l4 * 4 + r;
                #pragma unroll
                for (int n = 0; n < 4; ++n) {
                    int col = bn * 128 + wc * 64 + n * 16 + l15;
                    Wct[(size_t)row * 512 + col] = f2b(acc[m][n][r]);
                }
            }
    } else {
        int s = (b - 32) * 4 + wid;
        float v = cmf[s];
        int n = 0;
        int* rt = routes + s * K_NB;
        for (int j0 = 0; j0 < S_LEN; j0 += 64) {
            float c = cmf[j0 + lane];
            bool m = (c == v);
            unsigned long long mask = __ballot(m);
            if (m) {
                int idx = n + __popcll(mask & ((1ull << lane) - 1ull));
                if (idx < K_NB) rt[idx] = j0 + lane;
            }
            n += __popcll(mask);
        }
        if (lane == 0) counts[s] = n < K_NB ? n : K_NB;
    }
}

// ---------------------------------------------------------------------------
// Final fused GEMM: out = x + avg_rows(x) @ Wc + bc
// A = group-avg of fp32 x rows (n==1 fast path = straight convert);
// B = Wct bf16 [n][k]; epilogue adds residual x and bc.
// 64x128 tile, BK=64, 4 waves, 256 blocks, reg-pipelined (round-5 structure).
// ---------------------------------------------------------------------------
__global__ __launch_bounds__(256) void gemmF_kernel(
    const float* __restrict__ x, const unsigned short* __restrict__ Wct,
    const float* __restrict__ bc, const int* __restrict__ routes,
    const int* __restrict__ counts, float* __restrict__ out) {
    __shared__ char lds[(64 + 128) * 64 * 2];
    char* As = lds;
    char* Bs = lds + 64 * 64 * 2;
    const int tid = threadIdx.x;
    const int bn = blockIdx.x, bm = blockIdx.y;
    const int wid = tid >> 6, lane = tid & 63;
    const int wr = wid >> 1, wc = wid & 1;
    const int l15 = lane & 15, l4 = lane >> 4;
    const int arow = tid >> 2, akq = (tid & 3) * 16;
    const int brow = tid >> 1, bkh = (tid & 1) * 32;

    const int grow = bm * 64 + arow;
    const int gs = grow & (S_LEN - 1), gb = grow >> 11;
    const int gn = counts[gs];
    const int* grt = routes + gs * K_NB;
    const float ginv = 1.0f / (float)gn;
    const float* xrow = x + (size_t)grow * 512;
    const size_t hbase = (size_t)gb * S_LEN * 512;
    const unsigned short* bsrc = Wct + (size_t)(bn * 128 + brow) * 512 + bkh;

    u32x4 arg[2], brg[4];
    auto load_a = [&](int k0) {
        unsigned short tmp[16];
        if (gn == 1) {
            const float* p = xrow + k0 + akq;
            #pragma unroll
            for (int i = 0; i < 4; ++i) {
                float4 v = *(const float4*)(p + i * 4);
                tmp[i*4+0] = f2b(v.x); tmp[i*4+1] = f2b(v.y);
                tmp[i*4+2] = f2b(v.z); tmp[i*4+3] = f2b(v.w);
            }
        } else {
            float av[16] = {};
            for (int e = 0; e < gn; ++e) {
                const float* p = x + hbase + (size_t)grt[e] * 512 + k0 + akq;
                #pragma unroll
                for (int i = 0; i < 4; ++i) {
                    float4 v = *(const float4*)(p + i * 4);
                    av[i*4+0] += v.x; av[i*4+1] += v.y;
                    av[i*4+2] += v.z; av[i*4+3] += v.w;
                }
            }
            #pragma unroll
            for (int i = 0; i < 16; ++i) tmp[i] = f2b(av[i] * ginv);
        }
        arg[0] = *(u32x4*)&tmp[0];
        arg[1] = *(u32x4*)&tmp[8];
    };
    auto load_b = [&](int k0) {
        #pragma unroll
        for (int i = 0; i < 4; ++i) brg[i] = *(const u32x4*)(bsrc + k0 + i * 8);
    };

    f32x4 acc[2][4] = {};
    load_a(0); load_b(0);
    for (int k0 = 0; k0 < 512; k0 += 64) {
        *(u32x4*)(As + swoff(arow, akq))     = arg[0];
        *(u32x4*)(As + swoff(arow, akq + 8)) = arg[1];
        #pragma unroll
        for (int i = 0; i < 4; ++i)
            *(u32x4*)(Bs + swoff(brow, bkh + i * 8)) = brg[i];
        __syncthreads();
        if (k0 + 64 < 512) { load_a(k0 + 64); load_b(k0 + 64); }
        #pragma unroll
        for (int kk = 0; kk < 2; ++kk) {
            const int kb = kk * 32 + l4 * 8;
            bf16x8 af[2], bg[4];
            #pragma unroll
            for (int m = 0; m < 2; ++m)
                af[m] = *(bf16x8*)(As + swoff(wr * 32 + m * 16 + l15, kb));
            #pragma unroll
            for (int n = 0; n < 4; ++n)
                bg[n] = *(bf16x8*)(Bs + swoff(wc * 64 + n * 16 + l15, kb));
            #pragma unroll
            for (int m = 0; m < 2; ++m)
                #pragma unroll
                for (int n = 0; n < 4; ++n)
                    acc[m][n] = __builtin_amdgcn_mfma_f32_16x16x32_bf16(
                        af[m], bg[n], acc[m][n], 0, 0, 0);
        }
        __syncthreads();
    }

    float bv[4];
    #pragma unroll
    for (int n = 0; n < 4; ++n) bv[n] = bc[bn * 128 + wc * 64 + n * 16 + l15];
    #pragma unroll
    for (int m = 0; m < 2; ++m)
        #pragma unroll
        for (int r = 0; r < 4; ++r) {
            int row = bm * 64 + wr * 32 + m * 16 + l4 * 4 + r;
            #pragma unroll
            for (int n = 0; n < 4; ++n) {
                int col = bn * 128 + wc * 64 + n * 16 + l15;
                float v = acc[m][n][r] + bv[n];
                out[(size_t)row * 512 + col] = x[(size_t)row * 512 + col] + v;
            }
        }
}

extern "C" void kernel_launch(void* const* d_in, const int* in_sizes, int n_in,
                              void* d_out, int out_size, void* d_ws, size_t ws_size,
                              hipStream_t stream) {
    const float* x     = (const float*)d_in[0];
    const float* W_in  = (const float*)d_in[1];
    const float* b_in  = (const float*)d_in[2];
    const float* W_out = (const float*)d_in[3];
    const float* b_out = (const float*)d_in[4];
    float* out = (float*)d_out;

    char* ws = (char*)d_ws;
    float*          cmf    = (float*)ws;                                  // 8 KB
    int*            counts = (int*)(ws + 8192);                           // 8 KB
    int*            routes = (int*)(ws + 16384);                          // 512 KB
    unsigned short* Wb_in  = (unsigned short*)(ws + 16384 + 524288);      // 512 KB
    unsigned short* Wt_out = (unsigned short*)(ws + 16384 + 2 * 524288);  // 512 KB
    unsigned short* Wct    = (unsigned short*)(ws + 16384 + 3 * 524288);  // 512 KB
    float*          bc     = (float*)(ws + 16384 + 4 * 524288);           // 2 KB

    prep_kernel<<<266, 256, 0, stream>>>(W_in, W_out, b_in, b_out,
                                         Wb_in, Wt_out, cmf, bc);
    mid_kernel<<<544, 256, 0, stream>>>(cmf, routes, counts,
                                        Wt_out, Wb_in, Wct);
    gemmF_kernel<<<dim3(4, 64), 256, 0, stream>>>(x, Wct, bc,
                                                  routes, counts, out);
}

// Round 7
// 34.592 us; speedup vs baseline: 1.4914x; 1.4914x over previous
//
#include <hip/hip_runtime.h>
#include <hip/hip_bf16.h>

#define S_LEN 2048
#define K_NB  64

typedef __attribute__((ext_vector_type(8))) short bf16x8;
typedef __attribute__((ext_vector_type(4))) float f32x4;
typedef __attribute__((ext_vector_type(4))) unsigned int u32x4;

__device__ inline unsigned short f2b(float f) {
    unsigned u = __builtin_bit_cast(unsigned, f);
    return (unsigned short)((u + 0x7FFFu + ((u >> 16) & 1u)) >> 16);  // RNE
}

// XOR-swizzled byte offset in a [rows][64] bf16 LDS tile (T2).
__device__ inline int swoff(int row, int k) {
    int o = row * 128 + k * 2;
    return o ^ ((row & 7) << 4);
}

// ---------------------------------------------------------------------------
// prep: b<128 : W_in  -> Wb_in  bf16 [k][n] (straight convert)
//       b<256 : W_out -> Wt_out bf16 [n][k] (transpose + convert)
//       b<264 : cantor measure (fp32-faithful; exp via double)
//       b<272 : bc[n] = b_in @ W_out + b_out  (parallel: 4-way j-split + LDS)
// ---------------------------------------------------------------------------
__global__ __launch_bounds__(256) void prep_kernel(
    const float* __restrict__ W_in, const float* __restrict__ W_out,
    const float* __restrict__ b_in, const float* __restrict__ b_out,
    unsigned short* __restrict__ Wb_in, unsigned short* __restrict__ Wt_out,
    float* __restrict__ cmf, float* __restrict__ bc) {
    int b = blockIdx.x, tid = threadIdx.x;
    if (b < 128) {
        int base = (b * 256 + tid) * 8;
        float4 v0 = *(const float4*)(W_in + base);
        float4 v1 = *(const float4*)(W_in + base + 4);
        unsigned short t[8] = { f2b(v0.x), f2b(v0.y), f2b(v0.z), f2b(v0.w),
                                f2b(v1.x), f2b(v1.y), f2b(v1.z), f2b(v1.w) };
        *(u32x4*)(Wb_in + base) = *(u32x4*)t;
    } else if (b < 256) {
        int u = (b - 128) * 256 + tid;
        int n = u & 511, kc = (u >> 9) * 8;
        unsigned short t[8];
        #pragma unroll
        for (int j = 0; j < 8; ++j) t[j] = f2b(W_out[(size_t)(kc + j) * 512 + n]);
        *(u32x4*)(Wt_out + (size_t)n * 512 + kc) = *(u32x4*)t;
    } else if (b < 264) {
        int s = (b - 256) * 256 + tid;
        float pos = ((float)s + 0.5f) * (1.0f / 2048.0f);
        float cm = 0.0f, scale = 1.0f, lvlw = 1.0f;
        #pragma unroll
        for (int k = 1; k <= 5; ++k) {
            scale *= 3.0f; lvlw *= 0.5f;
            float y = fmodf(pos * scale, 3.0f);
            float d0 = y - 0.5f, d1 = y - 1.5f, d2 = y - 2.5f;
            float l0 = -(d0 * d0) * 4.0f;   // /(0.25+1e-10) == *4 in fp32
            float l1 = -(d1 * d1) * 4.0f;
            float l2 = -(d2 * d2) * 4.0f;
            float m = fmaxf(l0, fmaxf(l1, l2));
            float e0 = (float)exp((double)(l0 - m));
            float e1 = (float)exp((double)(l1 - m));
            float e2 = (float)exp((double)(l2 - m));
            float sum = (e0 + e1) + e2;
            float p1 = e1 / sum, p2 = e2 / sum;
            cm += (p2 + 0.5f * p1) * lvlw;
        }
        cmf[s] = cm;
    } else {
        __shared__ float red[4][64];
        int bb = b - 264;                 // 0..7
        int nl = tid & 63, jc = tid >> 6; // 4-way j split
        int n = bb * 64 + nl;
        float acc = 0.0f;
        #pragma unroll 8
        for (int j = jc * 128; j < jc * 128 + 128; ++j)
            acc += b_in[j] * W_out[(size_t)j * 512 + n];
        red[jc][nl] = acc;
        __syncthreads();
        if (jc == 0)
            bc[n] = b_out[n] + ((red[0][nl] + red[1][nl]) +
                                (red[2][nl] + red[3][nl]));
    }
}

// ---------------------------------------------------------------------------
// mid: b<32  : Wct[n][k] = (W_in@W_out)^T in bf16 via MFMA (64x128 tile)
//      b>=32 : exact-equality grouping (ballot+prefix, ascending order =
//              lax.top_k tie-break; non-equal softmax weights underflow to 0)
// ---------------------------------------------------------------------------
__global__ __launch_bounds__(256) void mid_kernel(
    const float* __restrict__ cmf, int* __restrict__ routes,
    int* __restrict__ counts,
    const unsigned short* __restrict__ Wt_out,
    const unsigned short* __restrict__ Wb_in,
    unsigned short* __restrict__ Wct) {
    __shared__ char lds[(64 + 128) * 64 * 2];
    int b = blockIdx.x, tid = threadIdx.x;
    int wid = tid >> 6, lane = tid & 63;
    if (b < 32) {
        char* As = lds;
        char* Bs = lds + 64 * 64 * 2;
        int bm = b >> 2, bn = b & 3;
        int wr = wid >> 1, wc = wid & 1;
        int l15 = lane & 15, l4 = lane >> 4;
        int arow = tid >> 2, akq = (tid & 3) * 16;
        int brow = tid >> 1, bkh = (tid & 1) * 32;
        const unsigned short* asrc = Wt_out + (size_t)(bm * 64 + arow) * 512 + akq;
        const unsigned short* bsrc = Wb_in + (size_t)(bn * 128 + brow) * 512 + bkh;
        u32x4 arg[2], brg[4];
        auto la = [&](int k0) {
            arg[0] = *(const u32x4*)(asrc + k0);
            arg[1] = *(const u32x4*)(asrc + k0 + 8);
        };
        auto lb = [&](int k0) {
            #pragma unroll
            for (int i = 0; i < 4; ++i) brg[i] = *(const u32x4*)(bsrc + k0 + i * 8);
        };
        f32x4 acc[2][4] = {};
        la(0); lb(0);
        for (int k0 = 0; k0 < 512; k0 += 64) {
            *(u32x4*)(As + swoff(arow, akq))     = arg[0];
            *(u32x4*)(As + swoff(arow, akq + 8)) = arg[1];
            #pragma unroll
            for (int i = 0; i < 4; ++i)
                *(u32x4*)(Bs + swoff(brow, bkh + i * 8)) = brg[i];
            __syncthreads();
            if (k0 + 64 < 512) { la(k0 + 64); lb(k0 + 64); }
            #pragma unroll
            for (int kk = 0; kk < 2; ++kk) {
                const int kb = kk * 32 + l4 * 8;
                bf16x8 af[2], bg[4];
                #pragma unroll
                for (int m = 0; m < 2; ++m)
                    af[m] = *(bf16x8*)(As + swoff(wr * 32 + m * 16 + l15, kb));
                #pragma unroll
                for (int n = 0; n < 4; ++n)
                    bg[n] = *(bf16x8*)(Bs + swoff(wc * 64 + n * 16 + l15, kb));
                #pragma unroll
                for (int m = 0; m < 2; ++m)
                    #pragma unroll
                    for (int n = 0; n < 4; ++n)
                        acc[m][n] = __builtin_amdgcn_mfma_f32_16x16x32_bf16(
                            af[m], bg[n], acc[m][n], 0, 0, 0);
            }
            __syncthreads();
        }
        #pragma unroll
        for (int m = 0; m < 2; ++m)
            #pragma unroll
            for (int r = 0; r < 4; ++r) {
                int row = bm * 64 + wr * 32 + m * 16 + l4 * 4 + r;
                #pragma unroll
                for (int n = 0; n < 4; ++n) {
                    int col = bn * 128 + wc * 64 + n * 16 + l15;
                    Wct[(size_t)row * 512 + col] = f2b(acc[m][n][r]);
                }
            }
    } else {
        int s = (b - 32) * 4 + wid;
        float v = cmf[s];
        int n = 0;
        int* rt = routes + s * K_NB;
        for (int j0 = 0; j0 < S_LEN; j0 += 64) {
            float c = cmf[j0 + lane];
            bool m = (c == v);
            unsigned long long mask = __ballot(m);
            if (m) {
                int idx = n + __popcll(mask & ((1ull << lane) - 1ull));
                if (idx < K_NB) rt[idx] = j0 + lane;
            }
            n += __popcll(mask);
        }
        if (lane == 0) counts[s] = n < K_NB ? n : K_NB;
    }
}

// ---------------------------------------------------------------------------
// avgx: xa[row][:] = bf16( (1/n) * sum_{k<n} x[b, routes[s,k], :] )
// Each averaged row computed exactly ONCE (plateau groups were previously
// recomputed 8x per K-step x per column-block inside the GEMM).
// 256 blocks x 256 threads; thread = (row-of-16, 32-col chunk).
// ---------------------------------------------------------------------------
__global__ __launch_bounds__(256) void avgx_kernel(
    const float* __restrict__ x, const int* __restrict__ routes,
    const int* __restrict__ counts, unsigned short* __restrict__ xa) {
    int tid = threadIdx.x;
    int row = blockIdx.x * 16 + (tid >> 4);   // 0..4095
    int c0 = (tid & 15) * 32;
    int s = row & (S_LEN - 1), bidx = row >> 11;
    int gn = counts[s];
    unsigned short* dst = xa + (size_t)row * 512 + c0;
    unsigned short t[32];
    if (gn == 1) {
        const float* p = x + (size_t)row * 512 + c0;
        #pragma unroll
        for (int i = 0; i < 8; ++i) {
            float4 v = *(const float4*)(p + i * 4);
            t[i*4+0] = f2b(v.x); t[i*4+1] = f2b(v.y);
            t[i*4+2] = f2b(v.z); t[i*4+3] = f2b(v.w);
        }
    } else {
        const int* rt = routes + s * K_NB;
        const float* xb = x + (size_t)bidx * S_LEN * 512 + c0;
        float av[32] = {};
        for (int e = 0; e < gn; ++e) {
            const float* p = xb + (size_t)rt[e] * 512;
            #pragma unroll
            for (int i = 0; i < 8; ++i) {
                float4 v = *(const float4*)(p + i * 4);
                av[i*4+0] += v.x; av[i*4+1] += v.y;
                av[i*4+2] += v.z; av[i*4+3] += v.w;
            }
        }
        float ginv = 1.0f / (float)gn;
        #pragma unroll
        for (int i = 0; i < 32; ++i) t[i] = f2b(av[i] * ginv);
    }
    #pragma unroll
    for (int i = 0; i < 4; ++i)
        *(u32x4*)(dst + i * 8) = *(u32x4*)&t[i * 8];
}

// ---------------------------------------------------------------------------
// Final GEMM: out = x + xa @ Wct^T + bc   (xa bf16, Wct bf16 [n][k])
// BM=64 x BN=64, BK=64, 4 waves, 512 blocks (2/CU), reg-pipelined.
// XCD-chunked swizzle: the 8 bn-blocks of one bm-panel share an XCD.
// ---------------------------------------------------------------------------
__global__ __launch_bounds__(256) void gemmF_kernel(
    const float* __restrict__ x, const unsigned short* __restrict__ xa,
    const unsigned short* __restrict__ Wct, const float* __restrict__ bc,
    float* __restrict__ out) {
    __shared__ char lds[2 * 64 * 64 * 2];   // As 8KB | Bs 8KB
    char* As = lds;
    char* Bs = lds + 64 * 64 * 2;
    const int tid = threadIdx.x;
    const int id = blockIdx.x;              // 0..511
    const int xcd = id & 7, slot = id >> 3;
    const int bm = xcd * 8 + (slot & 7);    // 0..63
    const int bn = slot >> 3;               // 0..7
    const int wid = tid >> 6, lane = tid & 63;
    const int wr = wid >> 1, wc = wid & 1;
    const int l15 = lane & 15, l4 = lane >> 4;
    const int arow = tid >> 2, akq = (tid & 3) * 16;

    const unsigned short* asrc = xa  + (size_t)(bm * 64 + arow) * 512 + akq;
    const unsigned short* bsrc = Wct + (size_t)(bn * 64 + arow) * 512 + akq;

    u32x4 arg[2], brg[2];
    auto la = [&](int k0) {
        arg[0] = *(const u32x4*)(asrc + k0);
        arg[1] = *(const u32x4*)(asrc + k0 + 8);
    };
    auto lb = [&](int k0) {
        brg[0] = *(const u32x4*)(bsrc + k0);
        brg[1] = *(const u32x4*)(bsrc + k0 + 8);
    };

    f32x4 acc[2][2] = {};
    la(0); lb(0);
    for (int k0 = 0; k0 < 512; k0 += 64) {
        *(u32x4*)(As + swoff(arow, akq))     = arg[0];
        *(u32x4*)(As + swoff(arow, akq + 8)) = arg[1];
        *(u32x4*)(Bs + swoff(arow, akq))     = brg[0];
        *(u32x4*)(Bs + swoff(arow, akq + 8)) = brg[1];
        __syncthreads();
        if (k0 + 64 < 512) { la(k0 + 64); lb(k0 + 64); }
        #pragma unroll
        for (int kk = 0; kk < 2; ++kk) {
            const int kb = kk * 32 + l4 * 8;
            bf16x8 af[2], bg[2];
            #pragma unroll
            for (int m = 0; m < 2; ++m)
                af[m] = *(bf16x8*)(As + swoff(wr * 32 + m * 16 + l15, kb));
            #pragma unroll
            for (int n = 0; n < 2; ++n)
                bg[n] = *(bf16x8*)(Bs + swoff(wc * 32 + n * 16 + l15, kb));
            #pragma unroll
            for (int m = 0; m < 2; ++m)
                #pragma unroll
                for (int n = 0; n < 2; ++n)
                    acc[m][n] = __builtin_amdgcn_mfma_f32_16x16x32_bf16(
                        af[m], bg[n], acc[m][n], 0, 0, 0);
        }
        __syncthreads();
    }

    float bv[2];
    #pragma unroll
    for (int n = 0; n < 2; ++n) bv[n] = bc[bn * 64 + wc * 32 + n * 16 + l15];
    #pragma unroll
    for (int m = 0; m < 2; ++m)
        #pragma unroll
        for (int r = 0; r < 4; ++r) {
            int row = bm * 64 + wr * 32 + m * 16 + l4 * 4 + r;
            #pragma unroll
            for (int n = 0; n < 2; ++n) {
                int col = bn * 64 + wc * 32 + n * 16 + l15;
                float v = acc[m][n][r] + bv[n];
                out[(size_t)row * 512 + col] = x[(size_t)row * 512 + col] + v;
            }
        }
}

extern "C" void kernel_launch(void* const* d_in, const int* in_sizes, int n_in,
                              void* d_out, int out_size, void* d_ws, size_t ws_size,
                              hipStream_t stream) {
    const float* x     = (const float*)d_in[0];
    const float* W_in  = (const float*)d_in[1];
    const float* b_in  = (const float*)d_in[2];
    const float* W_out = (const float*)d_in[3];
    const float* b_out = (const float*)d_in[4];
    float* out = (float*)d_out;

    char* ws = (char*)d_ws;
    float*          cmf    = (float*)ws;                                  // 8 KB
    int*            counts = (int*)(ws + 8192);                           // 8 KB
    int*            routes = (int*)(ws + 16384);                          // 512 KB
    unsigned short* Wb_in  = (unsigned short*)(ws + 16384 + 524288);      // 512 KB
    unsigned short* Wt_out = (unsigned short*)(ws + 16384 + 2 * 524288);  // 512 KB
    unsigned short* Wct    = (unsigned short*)(ws + 16384 + 3 * 524288);  // 512 KB
    float*          bc     = (float*)(ws + 16384 + 4 * 524288);           // 2 KB
    unsigned short* xa     = (unsigned short*)(ws + 16384 + 4 * 524288 + 4096); // 4 MB

    prep_kernel<<<272, 256, 0, stream>>>(W_in, W_out, b_in, b_out,
                                         Wb_in, Wt_out, cmf, bc);
    mid_kernel<<<544, 256, 0, stream>>>(cmf, routes, counts,
                                        Wt_out, Wb_in, Wct);
    avgx_kernel<<<256, 256, 0, stream>>>(x, routes, counts, xa);
    gemmF_kernel<<<512, 256, 0, stream>>>(x, xa, Wct, bc, out);
}